// Round 5
// baseline (386.452 us; speedup 1.0000x reference)
//
#include <hip/hip_runtime.h>
#include <hip/hip_bf16.h>

// B=8, C=512, N=2048, P=256.
// Round 5: (a) y GEMM 128x128 tiles (halve fbf HBM re-fetch),
//          (b) BN stats fused into z-GEMM epilogue (atomics) -> bn_stats gone,
//          (c) z stored bf16 (stats from fp32 accums) -> halve z r/w traffic.
// Numerics: theta/phi/scores split-bf16 (3 MFMAs, fp32-class logits);
//           g, f, y, z plain bf16 (post-softmax, not exp-amplified).

typedef __attribute__((ext_vector_type(8))) short short8;
typedef __attribute__((ext_vector_type(4))) float floatx4;

#define AS1 __attribute__((address_space(1)))
#define AS3 __attribute__((address_space(3)))

__device__ __forceinline__ void stage16(const unsigned short* gp, unsigned short* lp) {
    __builtin_amdgcn_global_load_lds((const AS1 void*)gp, (AS3 void*)lp, 16, 0, 0);
}

// ---------------- bf16 helpers ----------------
__device__ __forceinline__ unsigned short f2bf(float v) {
    __hip_bfloat16 h = __float2bfloat16(v);
    return *(unsigned short*)&h;
}
__device__ __forceinline__ float bf2f(unsigned short u) {
    __hip_bfloat16 h;
    *(unsigned short*)&h = u;
    return __bfloat162float(h);
}

// transpose + hi/lo split: X [R][N] fp32 -> Thi/Tlo [N][R] bf16 (batched over z)
__global__ __launch_bounds__(256) void transpose_split(
    const float* __restrict__ X, unsigned short* __restrict__ Thi,
    unsigned short* __restrict__ Tlo, int R, int N)
{
    X   += (long)blockIdx.z * R * N;
    Thi += (long)blockIdx.z * N * R;
    Tlo += (long)blockIdx.z * N * R;
    __shared__ float s[32][33];
    const int tx = threadIdx.x & 31, ty = threadIdx.x >> 5;
    const int n0 = blockIdx.x * 32, r0 = blockIdx.y * 32;
#pragma unroll
    for (int r = 0; r < 4; ++r)
        s[ty + r * 8][tx] = X[(long)(r0 + ty + r * 8) * N + n0 + tx];
    __syncthreads();
#pragma unroll
    for (int r = 0; r < 4; ++r) {
        const int n = ty + r * 8;
        const float v = s[tx][n];
        const unsigned short hi = f2bf(v);
        const unsigned short lo = f2bf(v - bf2f(hi));
        Thi[(long)(n0 + n) * R + r0 + tx] = hi;
        Tlo[(long)(n0 + n) * R + r0 + tx] = lo;
    }
}

__global__ __launch_bounds__(256) void split_w(
    const float* __restrict__ W, unsigned short* __restrict__ Whi,
    unsigned short* __restrict__ Wlo, int n)
{
    const int i = blockIdx.x * 256 + threadIdx.x;
    if (i < n) {
        const float v = W[i];
        const unsigned short hi = f2bf(v);
        Whi[i] = hi;
        Wlo[i] = f2bf(v - bf2f(hi));
    }
}

__global__ __launch_bounds__(256) void cast_bf16(
    const float* __restrict__ X, unsigned short* __restrict__ Y)
{
    const long i = ((long)blockIdx.x * 256 + threadIdx.x) * 4;
    const float4 v = *(const float4*)&X[i];
    ushort4 o;
    o.x = f2bf(v.x); o.y = f2bf(v.y); o.z = f2bf(v.z); o.w = f2bf(v.w);
    *(ushort4*)&Y[i] = o;
}

// ---------------- MFMA GEMM (m97-style) ----------------
// C[M][N] = A[M][K] * B[N][K]^T, bf16 K-contiguous inputs, fp32 accum.
// Tile: (FM*32) x (FN*32); 4 waves 2x2; wave tile 16FM x 16FN.
// SPLIT: C = Ah*Bh + Ah*Bl + Al*Bh.
// OUTMODE: 0 = fp32, 1 = bf16, 2 = hi/lo split bf16,
//          3 = bf16 + per-row (sum, sumsq) atomics into S1/S2 (BN stats).
#define BK 32

template <bool SPLIT, int OUTMODE, int FM, int FN>
__global__ __launch_bounds__(256) void mfma_gemm(
    const unsigned short* __restrict__ Ahi, const unsigned short* __restrict__ Alo,
    const unsigned short* __restrict__ Bhi, const unsigned short* __restrict__ Blo,
    void* __restrict__ Cout, void* __restrict__ Cout2,
    int K, int lda, int ldb, int ldc,
    long sA, long sB, long sC,
    float* __restrict__ S1, float* __restrict__ S2)
{
    constexpr int MTM = FM * 32, MTN = FN * 32;
    constexpr int nIA = MTM / 16, nIB = MTN / 16;

    Ahi += (long)blockIdx.z * sA;
    Bhi += (long)blockIdx.z * sB;
    if (SPLIT) { Alo += (long)blockIdx.z * sA; Blo += (long)blockIdx.z * sB; }
    float* Cf = (float*)Cout + (long)blockIdx.z * sC;
    unsigned short* Ch = (unsigned short*)Cout + (long)blockIdx.z * sC;
    unsigned short* Cl = (unsigned short*)Cout2 + (long)blockIdx.z * sC;

    __shared__ unsigned short AsH[MTM * BK], BsH[MTN * BK];
    __shared__ unsigned short AsL[SPLIT ? MTM * BK : 8], BsL[SPLIT ? MTN * BK : 8];

    const int tid = threadIdx.x;
    const int wid = tid >> 6, lane = tid & 63;
    const int wm = (wid >> 1) * (FM * 16), wn = (wid & 1) * (FN * 16);
    const int l15 = lane & 15, quad = lane >> 4;
    const int m0 = blockIdx.y * MTM, n0 = blockIdx.x * MTN;

    const int srow = lane >> 2;
    const int scol = (lane & 3) * 8;

    floatx4 acc[FM][FN];
#pragma unroll
    for (int i = 0; i < FM; ++i)
#pragma unroll
        for (int j = 0; j < FN; ++j) acc[i][j] = (floatx4){0.f, 0.f, 0.f, 0.f};

    for (int k0 = 0; k0 < K; k0 += BK) {
#pragma unroll
        for (int j = wid; j < nIA; j += 4) {
            const long off = (long)(m0 + j * 16 + srow) * lda + k0 + scol;
            stage16(Ahi + off, &AsH[j * 512]);
            if (SPLIT) stage16(Alo + off, &AsL[j * 512]);
        }
#pragma unroll
        for (int j = wid; j < nIB; j += 4) {
            const long off = (long)(n0 + j * 16 + srow) * ldb + k0 + scol;
            stage16(Bhi + off, &BsH[j * 512]);
            if (SPLIT) stage16(Blo + off, &BsL[j * 512]);
        }
        __syncthreads();

        short8 ah[FM], bh[FN], al[SPLIT ? FM : 1], bl[SPLIT ? FN : 1];
#pragma unroll
        for (int i = 0; i < FM; ++i) {
            ah[i] = *(const short8*)&AsH[(wm + i * 16 + l15) * BK + quad * 8];
            if (SPLIT) al[i] = *(const short8*)&AsL[(wm + i * 16 + l15) * BK + quad * 8];
        }
#pragma unroll
        for (int j = 0; j < FN; ++j) {
            bh[j] = *(const short8*)&BsH[(wn + j * 16 + l15) * BK + quad * 8];
            if (SPLIT) bl[j] = *(const short8*)&BsL[(wn + j * 16 + l15) * BK + quad * 8];
        }
#pragma unroll
        for (int i = 0; i < FM; ++i)
#pragma unroll
            for (int j = 0; j < FN; ++j) {
                acc[i][j] = __builtin_amdgcn_mfma_f32_16x16x32_bf16(ah[i], bh[j], acc[i][j], 0, 0, 0);
                if (SPLIT) {
                    acc[i][j] = __builtin_amdgcn_mfma_f32_16x16x32_bf16(ah[i], bl[j], acc[i][j], 0, 0, 0);
                    acc[i][j] = __builtin_amdgcn_mfma_f32_16x16x32_bf16(al[i], bh[j], acc[i][j], 0, 0, 0);
                }
            }
        __syncthreads();
    }

    // C/D layout: col = lane&15, row = quad*4 + reg
#pragma unroll
    for (int i = 0; i < FM; ++i)
#pragma unroll
        for (int j = 0; j < FN; ++j) {
            const int m = m0 + wm + i * 16 + quad * 4;
            const int n = n0 + wn + j * 16 + l15;
#pragma unroll
            for (int r = 0; r < 4; ++r) {
                const float v = acc[i][j][r];
                const long idx = (long)(m + r) * ldc + n;
                if (OUTMODE == 0) {
                    Cf[idx] = v;
                } else if (OUTMODE == 1 || OUTMODE == 3) {
                    Ch[idx] = f2bf(v);
                } else {
                    const unsigned short hi = f2bf(v);
                    Ch[idx] = hi;
                    Cl[idx] = f2bf(v - bf2f(hi));
                }
            }
        }

    if (OUTMODE == 3) {
        // per-row partial (sum, sumsq) over this wave's 16*FN columns, from fp32 accs
#pragma unroll
        for (int i = 0; i < FM; ++i)
#pragma unroll
            for (int r = 0; r < 4; ++r) {
                float s = 0.f, q = 0.f;
#pragma unroll
                for (int j = 0; j < FN; ++j) {
                    const float v = acc[i][j][r];
                    s += v; q += v * v;
                }
#pragma unroll
                for (int msk = 1; msk < 16; msk <<= 1) {
                    s += __shfl_xor(s, msk, 64);
                    q += __shfl_xor(q, msk, 64);
                }
                if (l15 == 0) {
                    const int row = m0 + wm + i * 16 + quad * 4 + r;
                    atomicAdd(&S1[row], s);
                    atomicAdd(&S2[row], q);
                }
            }
    }
}

// ---------------- softmax: fp32 chunk row -> bf16 full-f row ----------------
__global__ __launch_bounds__(256) void softmax_bf(
    const float* __restrict__ fin, unsigned short* __restrict__ fout,
    int N, int rowsPerBatch, int noff)
{
    const int b = blockIdx.x / rowsPerBatch;
    const int nc = blockIdx.x % rowsPerBatch;
    const float* p = fin + (long)blockIdx.x * N;
    unsigned short* q = fout + ((long)b * N + noff + nc) * N;
    const int tid = threadIdx.x;
    float v[8];
    float mx = -1e30f;
#pragma unroll
    for (int i = 0; i < 8; ++i) {
        v[i] = p[tid + i * 256];
        mx = fmaxf(mx, v[i]);
    }
    __shared__ float red[256];
    red[tid] = mx;
    __syncthreads();
    for (int s = 128; s > 0; s >>= 1) {
        if (tid < s) red[tid] = fmaxf(red[tid], red[tid + s]);
        __syncthreads();
    }
    mx = red[0];
    __syncthreads();
    float sum = 0.f;
#pragma unroll
    for (int i = 0; i < 8; ++i) {
        v[i] = __expf(v[i] - mx);
        sum += v[i];
    }
    red[tid] = sum;
    __syncthreads();
    for (int s = 128; s > 0; s >>= 1) {
        if (tid < s) red[tid] += red[tid + s];
        __syncthreads();
    }
    const float inv = 1.0f / red[0];
#pragma unroll
    for (int i = 0; i < 8; ++i) q[tid + i * 256] = f2bf(v[i] * inv);
}

// ---------------- BN finalize + apply ----------------
__global__ __launch_bounds__(256) void bn_finalize(
    const float* __restrict__ s, const float* __restrict__ q,
    float* __restrict__ mean, float* __restrict__ rstd, int C, float cnt)
{
    const int c = blockIdx.x * 256 + threadIdx.x;
    if (c < C) {
        const float m = s[c] / cnt;
        mean[c] = m;
        rstd[c] = rsqrtf(q[c] / cnt - m * m + 1e-5f);
    }
}

__global__ __launch_bounds__(256) void bn_apply_bf(
    const unsigned short* __restrict__ z, const float* __restrict__ x,
    const float* __restrict__ mean, const float* __restrict__ rstd,
    const float* __restrict__ gamma, const float* __restrict__ beta,
    float* __restrict__ out, int C, int N)
{
    const long i = ((long)blockIdx.x * 256 + threadIdx.x) * 8;
    const int c = (int)((i / N) % C);
    const float mu = mean[c], rs = rstd[c], ga = gamma[c], be = beta[c];
    const ushort4 z0 = *(const ushort4*)&z[i];
    const ushort4 z1 = *(const ushort4*)&z[i + 4];
    const float4 x0 = *(const float4*)&x[i];
    const float4 x1 = *(const float4*)&x[i + 4];
    float4 o0, o1;
    o0.x = (bf2f(z0.x) - mu) * rs * ga + be + x0.x;
    o0.y = (bf2f(z0.y) - mu) * rs * ga + be + x0.y;
    o0.z = (bf2f(z0.z) - mu) * rs * ga + be + x0.z;
    o0.w = (bf2f(z0.w) - mu) * rs * ga + be + x0.w;
    o1.x = (bf2f(z1.x) - mu) * rs * ga + be + x1.x;
    o1.y = (bf2f(z1.y) - mu) * rs * ga + be + x1.y;
    o1.z = (bf2f(z1.z) - mu) * rs * ga + be + x1.z;
    o1.w = (bf2f(z1.w) - mu) * rs * ga + be + x1.w;
    *(float4*)&out[i] = o0;
    *(float4*)&out[i + 4] = o1;
}

extern "C" void kernel_launch(void* const* d_in, const int* in_sizes, int n_in,
                              void* d_out, int out_size, void* d_ws, size_t ws_size,
                              hipStream_t stream)
{
    const int B = 8, C = 512, N = 2048, P = 256;
    const int NC = 512;                       // f row-chunk
    const float* x      = (const float*)d_in[0];
    const float* Wg     = (const float*)d_in[1];
    const float* Wtheta = (const float*)d_in[2];
    const float* Wphi   = (const float*)d_in[3];
    const float* Wz     = (const float*)d_in[4];
    const float* gamma  = (const float*)d_in[5];
    const float* beta   = (const float*)d_in[6];
    float* out = (float*)d_out;

    // ---- workspace layout (float units) ----
    float* ws = (float*)d_ws;
    const long NCle = (long)N * C;            // 1,048,576 per batch
    const long NP   = (long)N * P;            // 524,288 per batch
    const long R0   = (long)B * NCle;         // 8.39M floats
    unsigned short* xtH  = (unsigned short*)ws;                 // B*N*C
    unsigned short* xtL  = xtH + B * NCle;
    float*          f32c = ws;                                  // aliases xt (dead after g)
    unsigned short* zbf  = (unsigned short*)ws;                 // aliases f32c (dead after softmax)
    unsigned short* thH  = (unsigned short*)(ws + R0);          // B*N*P each
    unsigned short* thL  = thH + B * NP;
    unsigned short* phH  = thL + B * NP;
    unsigned short* phL  = phH + B * NP;
    unsigned short* gbf  = (unsigned short*)(ws + R0 + 4 * (B * NP / 2));  // B*P*N
    unsigned short* fbf  = gbf + B * NP;                        // B*N*N
    unsigned short* ybf  = fbf + (long)B * N * N;               // B*N*P
    unsigned short* WthH = ybf + B * NP;                        // P*C each
    unsigned short* WthL = WthH + (long)P * C;
    unsigned short* WphH = WthL + (long)P * C;
    unsigned short* WphL = WphH + (long)P * C;
    unsigned short* WgB  = WphL + (long)P * C;
    unsigned short* WzB  = WgB + (long)P * C;
    // BN scratch lives in thT region (dead after scores GEMMs)
    float*          bnsum = ws + R0;           // [C]
    float*          bnsq  = bnsum + C;         // [C]
    float*          mean  = bnsq + C;          // [C]
    float*          rstd  = mean + C;          // [C]

    const long sX = (long)C * N;

    // 1: transpose+split x -> xT hi/lo [B][N][C]
    transpose_split<<<dim3(N / 32, C / 32, B), 256, 0, stream>>>(x, xtH, xtL, C, N);
    // 2: weight preps
    split_w<<<(P * C + 255) / 256, 256, 0, stream>>>(Wtheta, WthH, WthL, P * C);
    split_w<<<(P * C + 255) / 256, 256, 0, stream>>>(Wphi, WphH, WphL, P * C);
    cast_bf16<<<P * C / 1024, 256, 0, stream>>>(Wg, WgB);
    cast_bf16<<<P * C / 1024, 256, 0, stream>>>(Wz, WzB);

    // 3: thT [B][N][P] = xT @ Wth^T (split, split-out)
    mfma_gemm<true, 2, 4, 2><<<dim3(P / 64, N / 128, B), 256, 0, stream>>>(
        xtH, xtL, WthH, WthL, thH, thL, C, C, C, P, NCle, 0, NP, nullptr, nullptr);
    // 4: phT
    mfma_gemm<true, 2, 4, 2><<<dim3(P / 64, N / 128, B), 256, 0, stream>>>(
        xtH, xtL, WphH, WphL, phH, phL, C, C, C, P, NCle, 0, NP, nullptr, nullptr);
    // 5: g [B][P][N] = Wg @ xT^T (plain, bf16 out)
    mfma_gemm<false, 1, 2, 4><<<dim3(N / 128, P / 64, B), 256, 0, stream>>>(
        WgB, WgB, xtH, xtH, gbf, gbf, C, C, C, N, 0, NCle, NP, nullptr, nullptr);

    // 6: scores (split) + softmax, chunked (f32c aliases xt: xt dead now)
    for (int c = 0; c < N / NC; ++c) {
        mfma_gemm<true, 0, 4, 4><<<dim3(N / 128, NC / 128, B), 256, 0, stream>>>(
            thH + (long)c * NC * P, thL + (long)c * NC * P, phH, phL, f32c, f32c,
            P, P, P, N, NP, NP, (long)NC * N, nullptr, nullptr);
        softmax_bf<<<B * NC, 256, 0, stream>>>(f32c, fbf, N, NC, c * NC);
    }

    // 7: yT [B][N][P] = fbf @ g^T (plain, bf16 out); 128x128 tiles -> fbf read 2x
    mfma_gemm<false, 1, 4, 4><<<dim3(P / 128, N / 128, B), 256, 0, stream>>>(
        fbf, fbf, gbf, gbf, ybf, ybf, N, N, N, P, (long)N * N, NP, NP, nullptr, nullptr);

    // 8: z [B][C][N] bf16 = Wz @ yT^T, BN stats fused (thT region dead now)
    hipMemsetAsync(bnsum, 0, 2 * C * sizeof(float), stream);
    mfma_gemm<false, 3, 4, 4><<<dim3(N / 128, C / 128, B), 256, 0, stream>>>(
        WzB, WzB, ybf, ybf, zbf, zbf, P, P, P, N, 0, NP, sX, bnsum, bnsq);

    // 9: BN finalize + apply + residual
    bn_finalize<<<(C + 255) / 256, 256, 0, stream>>>(bnsum, bnsq, mean, rstd, C, (float)B * N);
    bn_apply_bf<<<(int)((B * sX) / 2048), 256, 0, stream>>>(zbf, x, mean, rstd, gamma, beta, out, C, N);
}

// Round 6
// 377.017 us; speedup vs baseline: 1.0250x; 1.0250x over previous
//
#include <hip/hip_runtime.h>
#include <hip/hip_bf16.h>

// B=8, C=512, N=2048, P=256.
// Round 6: double-buffered pipelined K-loop in the MFMA engine (we run at
// 1-3 blocks/CU, so explicit prefetch-across-barrier pays, unlike m97's
// 3-block regime); occupancy-driven tile reshapes (scores FM4/FN2 @1024
// blocks, y FM2/FN4 @512); BN stats via per-block scratch partials
// (no atomics, no memset).
// Numerics: theta/phi/scores split-bf16 (3 MFMAs, fp32-class logits);
//           g, f, y, z plain bf16 (post-softmax, not exp-amplified).

typedef __attribute__((ext_vector_type(8))) short short8;
typedef __attribute__((ext_vector_type(4))) float floatx4;

#define AS1 __attribute__((address_space(1)))
#define AS3 __attribute__((address_space(3)))

__device__ __forceinline__ void stage16(const unsigned short* gp, unsigned short* lp) {
    __builtin_amdgcn_global_load_lds((const AS1 void*)gp, (AS3 void*)lp, 16, 0, 0);
}

// ---------------- bf16 helpers ----------------
__device__ __forceinline__ unsigned short f2bf(float v) {
    __hip_bfloat16 h = __float2bfloat16(v);
    return *(unsigned short*)&h;
}
__device__ __forceinline__ float bf2f(unsigned short u) {
    __hip_bfloat16 h;
    *(unsigned short*)&h = u;
    return __bfloat162float(h);
}

// transpose + hi/lo split: X [R][N] fp32 -> Thi/Tlo [N][R] bf16 (batched over z)
__global__ __launch_bounds__(256) void transpose_split(
    const float* __restrict__ X, unsigned short* __restrict__ Thi,
    unsigned short* __restrict__ Tlo, int R, int N)
{
    X   += (long)blockIdx.z * R * N;
    Thi += (long)blockIdx.z * N * R;
    Tlo += (long)blockIdx.z * N * R;
    __shared__ float s[32][33];
    const int tx = threadIdx.x & 31, ty = threadIdx.x >> 5;
    const int n0 = blockIdx.x * 32, r0 = blockIdx.y * 32;
#pragma unroll
    for (int r = 0; r < 4; ++r)
        s[ty + r * 8][tx] = X[(long)(r0 + ty + r * 8) * N + n0 + tx];
    __syncthreads();
#pragma unroll
    for (int r = 0; r < 4; ++r) {
        const int n = ty + r * 8;
        const float v = s[tx][n];
        const unsigned short hi = f2bf(v);
        const unsigned short lo = f2bf(v - bf2f(hi));
        Thi[(long)(n0 + n) * R + r0 + tx] = hi;
        Tlo[(long)(n0 + n) * R + r0 + tx] = lo;
    }
}

__global__ __launch_bounds__(256) void split_w(
    const float* __restrict__ W, unsigned short* __restrict__ Whi,
    unsigned short* __restrict__ Wlo, int n)
{
    const int i = blockIdx.x * 256 + threadIdx.x;
    if (i < n) {
        const float v = W[i];
        const unsigned short hi = f2bf(v);
        Whi[i] = hi;
        Wlo[i] = f2bf(v - bf2f(hi));
    }
}

__global__ __launch_bounds__(256) void cast_bf16(
    const float* __restrict__ X, unsigned short* __restrict__ Y)
{
    const long i = ((long)blockIdx.x * 256 + threadIdx.x) * 4;
    const float4 v = *(const float4*)&X[i];
    ushort4 o;
    o.x = f2bf(v.x); o.y = f2bf(v.y); o.z = f2bf(v.z); o.w = f2bf(v.w);
    *(ushort4*)&Y[i] = o;
}

// ---------------- MFMA GEMM (double-buffered pipeline) ----------------
// C[M][N] = A[M][K] * B[N][K]^T, bf16 K-contiguous inputs, fp32 accum.
// Tile: (FM*32) x (FN*32); 4 waves 2x2; wave tile 16FM x 16FN.
// SPLIT: C = Ah*Bh + Ah*Bl + Al*Bh.
// OUTMODE: 0 = fp32, 1 = bf16, 2 = hi/lo split bf16,
//          3 = bf16 + per-row (sum,sumsq) partials into S1/S2 scratch
//              (slot = (bz*gridDim.x+bx)*2 + wave-n; 256 slots/row).
#define BK 32

template <bool SPLIT, int OUTMODE, int FM, int FN>
__global__ __launch_bounds__(256) void mfma_gemm(
    const unsigned short* __restrict__ Ahi, const unsigned short* __restrict__ Alo,
    const unsigned short* __restrict__ Bhi, const unsigned short* __restrict__ Blo,
    void* __restrict__ Cout, void* __restrict__ Cout2,
    int K, int lda, int ldb, int ldc,
    long sA, long sB, long sC,
    float* __restrict__ S1, float* __restrict__ S2)
{
    constexpr int MTM = FM * 32, MTN = FN * 32;
    constexpr int nIA = MTM / 16, nIB = MTN / 16;

    Ahi += (long)blockIdx.z * sA;
    Bhi += (long)blockIdx.z * sB;
    if (SPLIT) { Alo += (long)blockIdx.z * sA; Blo += (long)blockIdx.z * sB; }
    float* Cf = (float*)Cout + (long)blockIdx.z * sC;
    unsigned short* Ch = (unsigned short*)Cout + (long)blockIdx.z * sC;
    unsigned short* Cl = (unsigned short*)Cout2 + (long)blockIdx.z * sC;

    __shared__ unsigned short AsH[2][MTM * BK], BsH[2][MTN * BK];
    __shared__ unsigned short AsL[SPLIT ? 2 : 1][SPLIT ? MTM * BK : 8];
    __shared__ unsigned short BsL[SPLIT ? 2 : 1][SPLIT ? MTN * BK : 8];

    const int tid = threadIdx.x;
    const int wid = tid >> 6, lane = tid & 63;
    const int wm = (wid >> 1) * (FM * 16), wn = (wid & 1) * (FN * 16);
    const int l15 = lane & 15, quad = lane >> 4;
    const int m0 = blockIdx.y * MTM, n0 = blockIdx.x * MTN;

    const int srow = lane >> 2;
    const int scol = (lane & 3) * 8;

    floatx4 acc[FM][FN];
#pragma unroll
    for (int i = 0; i < FM; ++i)
#pragma unroll
        for (int j = 0; j < FN; ++j) acc[i][j] = (floatx4){0.f, 0.f, 0.f, 0.f};

    auto stage = [&](int k0, int buf) {
#pragma unroll
        for (int j = wid; j < nIA; j += 4) {
            const long off = (long)(m0 + j * 16 + srow) * lda + k0 + scol;
            stage16(Ahi + off, &AsH[buf][j * 512]);
            if (SPLIT) stage16(Alo + off, &AsL[buf][j * 512]);
        }
#pragma unroll
        for (int j = wid; j < nIB; j += 4) {
            const long off = (long)(n0 + j * 16 + srow) * ldb + k0 + scol;
            stage16(Bhi + off, &BsH[buf][j * 512]);
            if (SPLIT) stage16(Blo + off, &BsL[buf][j * 512]);
        }
    };

    const int iters = K / BK;
    stage(0, 0);
    for (int it = 0; it < iters; ++it) {
        const int cur = it & 1;
        __syncthreads();                 // drains tile-it loads (issued 1 iter ago)
        if (it + 1 < iters) stage((it + 1) * BK, cur ^ 1);   // prefetch across compute

        short8 ah[FM], bh[FN], al[SPLIT ? FM : 1], bl[SPLIT ? FN : 1];
#pragma unroll
        for (int i = 0; i < FM; ++i) {
            ah[i] = *(const short8*)&AsH[cur][(wm + i * 16 + l15) * BK + quad * 8];
            if (SPLIT) al[i] = *(const short8*)&AsL[cur][(wm + i * 16 + l15) * BK + quad * 8];
        }
#pragma unroll
        for (int j = 0; j < FN; ++j) {
            bh[j] = *(const short8*)&BsH[cur][(wn + j * 16 + l15) * BK + quad * 8];
            if (SPLIT) bl[j] = *(const short8*)&BsL[cur][(wn + j * 16 + l15) * BK + quad * 8];
        }
#pragma unroll
        for (int i = 0; i < FM; ++i)
#pragma unroll
            for (int j = 0; j < FN; ++j) {
                acc[i][j] = __builtin_amdgcn_mfma_f32_16x16x32_bf16(ah[i], bh[j], acc[i][j], 0, 0, 0);
                if (SPLIT) {
                    acc[i][j] = __builtin_amdgcn_mfma_f32_16x16x32_bf16(ah[i], bl[j], acc[i][j], 0, 0, 0);
                    acc[i][j] = __builtin_amdgcn_mfma_f32_16x16x32_bf16(al[i], bh[j], acc[i][j], 0, 0, 0);
                }
            }
    }

    // C/D layout: col = lane&15, row = quad*4 + reg
#pragma unroll
    for (int i = 0; i < FM; ++i)
#pragma unroll
        for (int j = 0; j < FN; ++j) {
            const int m = m0 + wm + i * 16 + quad * 4;
            const int n = n0 + wn + j * 16 + l15;
#pragma unroll
            for (int r = 0; r < 4; ++r) {
                const float v = acc[i][j][r];
                const long idx = (long)(m + r) * ldc + n;
                if (OUTMODE == 0) {
                    Cf[idx] = v;
                } else if (OUTMODE == 1 || OUTMODE == 3) {
                    Ch[idx] = f2bf(v);
                } else {
                    const unsigned short hi = f2bf(v);
                    Ch[idx] = hi;
                    Cl[idx] = f2bf(v - bf2f(hi));
                }
            }
        }

    if (OUTMODE == 3) {
        // per-row (sum,sumsq) over this wave's 16*FN cols; no atomics
        const int slot = (blockIdx.z * gridDim.x + blockIdx.x) * 2 + (wn >> 6);
#pragma unroll
        for (int i = 0; i < FM; ++i)
#pragma unroll
            for (int r = 0; r < 4; ++r) {
                float s = 0.f, q = 0.f;
#pragma unroll
                for (int j = 0; j < FN; ++j) {
                    const float v = acc[i][j][r];
                    s += v; q += v * v;
                }
#pragma unroll
                for (int msk = 1; msk < 16; msk <<= 1) {
                    s += __shfl_xor(s, msk, 64);
                    q += __shfl_xor(q, msk, 64);
                }
                if (l15 == 0) {
                    const int row = m0 + wm + i * 16 + quad * 4 + r;
                    S1[(long)row * 256 + slot] = s;
                    S2[(long)row * 256 + slot] = q;
                }
            }
    }
}

// ---------------- softmax: fp32 chunk row -> bf16 full-f row ----------------
__global__ __launch_bounds__(256) void softmax_bf(
    const float* __restrict__ fin, unsigned short* __restrict__ fout,
    int N, int rowsPerBatch, int noff)
{
    const int b = blockIdx.x / rowsPerBatch;
    const int nc = blockIdx.x % rowsPerBatch;
    const float* p = fin + (long)blockIdx.x * N;
    unsigned short* q = fout + ((long)b * N + noff + nc) * N;
    const int tid = threadIdx.x;
    float v[8];
    float mx = -1e30f;
#pragma unroll
    for (int i = 0; i < 8; ++i) {
        v[i] = p[tid + i * 256];
        mx = fmaxf(mx, v[i]);
    }
    __shared__ float red[256];
    red[tid] = mx;
    __syncthreads();
    for (int s = 128; s > 0; s >>= 1) {
        if (tid < s) red[tid] = fmaxf(red[tid], red[tid + s]);
        __syncthreads();
    }
    mx = red[0];
    __syncthreads();
    float sum = 0.f;
#pragma unroll
    for (int i = 0; i < 8; ++i) {
        v[i] = __expf(v[i] - mx);
        sum += v[i];
    }
    red[tid] = sum;
    __syncthreads();
    for (int s = 128; s > 0; s >>= 1) {
        if (tid < s) red[tid] += red[tid + s];
        __syncthreads();
    }
    const float inv = 1.0f / red[0];
#pragma unroll
    for (int i = 0; i < 8; ++i) q[tid + i * 256] = f2bf(v[i] * inv);
}

// ---------------- BN finalize + apply ----------------
__global__ __launch_bounds__(256) void bn_finalize(
    const float* __restrict__ p1, const float* __restrict__ p2,
    float* __restrict__ mean, float* __restrict__ rstd, float cnt)
{
    const int c = blockIdx.x, t = threadIdx.x;
    __shared__ float rs[256], rq[256];
    rs[t] = p1[(long)c * 256 + t];
    rq[t] = p2[(long)c * 256 + t];
    __syncthreads();
    for (int st = 128; st > 0; st >>= 1) {
        if (t < st) { rs[t] += rs[t + st]; rq[t] += rq[t + st]; }
        __syncthreads();
    }
    if (t == 0) {
        const float m = rs[0] / cnt;
        mean[c] = m;
        rstd[c] = rsqrtf(rq[0] / cnt - m * m + 1e-5f);
    }
}

__global__ __launch_bounds__(256) void bn_apply_bf(
    const unsigned short* __restrict__ z, const float* __restrict__ x,
    const float* __restrict__ mean, const float* __restrict__ rstd,
    const float* __restrict__ gamma, const float* __restrict__ beta,
    float* __restrict__ out, int C, int N)
{
    const long i = ((long)blockIdx.x * 256 + threadIdx.x) * 8;
    const int c = (int)((i / N) % C);
    const float mu = mean[c], rs = rstd[c], ga = gamma[c], be = beta[c];
    const ushort4 z0 = *(const ushort4*)&z[i];
    const ushort4 z1 = *(const ushort4*)&z[i + 4];
    const float4 x0 = *(const float4*)&x[i];
    const float4 x1 = *(const float4*)&x[i + 4];
    float4 o0, o1;
    o0.x = (bf2f(z0.x) - mu) * rs * ga + be + x0.x;
    o0.y = (bf2f(z0.y) - mu) * rs * ga + be + x0.y;
    o0.z = (bf2f(z0.z) - mu) * rs * ga + be + x0.z;
    o0.w = (bf2f(z0.w) - mu) * rs * ga + be + x0.w;
    o1.x = (bf2f(z1.x) - mu) * rs * ga + be + x1.x;
    o1.y = (bf2f(z1.y) - mu) * rs * ga + be + x1.y;
    o1.z = (bf2f(z1.z) - mu) * rs * ga + be + x1.z;
    o1.w = (bf2f(z1.w) - mu) * rs * ga + be + x1.w;
    *(float4*)&out[i] = o0;
    *(float4*)&out[i + 4] = o1;
}

extern "C" void kernel_launch(void* const* d_in, const int* in_sizes, int n_in,
                              void* d_out, int out_size, void* d_ws, size_t ws_size,
                              hipStream_t stream)
{
    const int B = 8, C = 512, N = 2048, P = 256;
    const int NC = 512;                       // f row-chunk
    const float* x      = (const float*)d_in[0];
    const float* Wg     = (const float*)d_in[1];
    const float* Wtheta = (const float*)d_in[2];
    const float* Wphi   = (const float*)d_in[3];
    const float* Wz     = (const float*)d_in[4];
    const float* gamma  = (const float*)d_in[5];
    const float* beta   = (const float*)d_in[6];
    float* out = (float*)d_out;

    // ---- workspace layout (float units) ----
    float* ws = (float*)d_ws;
    const long NCle = (long)N * C;            // 1,048,576 per batch
    const long NP   = (long)N * P;            // 524,288 per batch
    const long R0   = (long)B * NCle;         // 8.39M floats
    unsigned short* xtH  = (unsigned short*)ws;                 // B*N*C
    unsigned short* xtL  = xtH + B * NCle;
    float*          f32c = ws;                                  // aliases xt (dead after g)
    unsigned short* zbf  = (unsigned short*)ws;                 // aliases f32c (dead after softmax)
    unsigned short* thH  = (unsigned short*)(ws + R0);          // B*N*P each
    unsigned short* thL  = thH + B * NP;
    unsigned short* phH  = thL + B * NP;
    unsigned short* phL  = phH + B * NP;
    unsigned short* gbf  = (unsigned short*)(ws + R0 + 4 * (B * NP / 2));  // B*P*N
    unsigned short* fbf  = gbf + B * NP;                        // B*N*N
    unsigned short* ybf  = fbf + (long)B * N * N;               // B*N*P
    unsigned short* WthH = ybf + B * NP;                        // P*C each
    unsigned short* WthL = WthH + (long)P * C;
    unsigned short* WphH = WthL + (long)P * C;
    unsigned short* WphL = WphH + (long)P * C;
    unsigned short* WgB  = WphL + (long)P * C;
    unsigned short* WzB  = WgB + (long)P * C;
    // BN scratch lives in thT region (dead after scores GEMMs)
    float*          bnp1 = ws + R0;            // [C][256]
    float*          bnp2 = bnp1 + (long)C * 256;
    float*          mean = bnp2 + (long)C * 256;
    float*          rstd = mean + C;

    const long sX = (long)C * N;

    // 1: transpose+split x -> xT hi/lo [B][N][C]
    transpose_split<<<dim3(N / 32, C / 32, B), 256, 0, stream>>>(x, xtH, xtL, C, N);
    // 2: weight preps
    split_w<<<(P * C + 255) / 256, 256, 0, stream>>>(Wtheta, WthH, WthL, P * C);
    split_w<<<(P * C + 255) / 256, 256, 0, stream>>>(Wphi, WphH, WphL, P * C);
    cast_bf16<<<P * C / 1024, 256, 0, stream>>>(Wg, WgB);
    cast_bf16<<<P * C / 1024, 256, 0, stream>>>(Wz, WzB);

    // 3: thT [B][N][P] = xT @ Wth^T (split, split-out); 128x64 tiles, 512 blocks
    mfma_gemm<true, 2, 4, 2><<<dim3(P / 64, N / 128, B), 256, 0, stream>>>(
        xtH, xtL, WthH, WthL, thH, thL, C, C, C, P, NCle, 0, NP, nullptr, nullptr);
    // 4: phT
    mfma_gemm<true, 2, 4, 2><<<dim3(P / 64, N / 128, B), 256, 0, stream>>>(
        xtH, xtL, WphH, WphL, phH, phL, C, C, C, P, NCle, 0, NP, nullptr, nullptr);
    // 5: g [B][P][N] = Wg @ xT^T (plain, bf16 out); 64x128 tiles, 512 blocks
    mfma_gemm<false, 1, 2, 4><<<dim3(N / 128, P / 64, B), 256, 0, stream>>>(
        WgB, WgB, xtH, xtH, gbf, gbf, C, C, C, N, 0, NCle, NP, nullptr, nullptr);

    // 6: scores (split) + softmax, chunked. 128x64 tiles -> 1024 blocks, 48KB LDS
    for (int c = 0; c < N / NC; ++c) {
        mfma_gemm<true, 0, 4, 2><<<dim3(N / 64, NC / 128, B), 256, 0, stream>>>(
            thH + (long)c * NC * P, thL + (long)c * NC * P, phH, phL, f32c, f32c,
            P, P, P, N, NP, NP, (long)NC * N, nullptr, nullptr);
        softmax_bf<<<B * NC, 256, 0, stream>>>(f32c, fbf, N, NC, c * NC);
    }

    // 7: yT [B][N][P] = fbf @ g^T (plain, bf16 out); 64x128 tiles -> 512 blocks,
    //    still only 2 column-tiles over P -> fbf fetched 2x
    mfma_gemm<false, 1, 2, 4><<<dim3(P / 128, N / 64, B), 256, 0, stream>>>(
        fbf, fbf, gbf, gbf, ybf, ybf, N, N, N, P, (long)N * N, NP, NP, nullptr, nullptr);

    // 8: z [B][C][N] bf16 = Wz @ yT^T, BN partials to scratch (no atomics)
    mfma_gemm<false, 3, 4, 4><<<dim3(N / 128, C / 128, B), 256, 0, stream>>>(
        WzB, WzB, ybf, ybf, zbf, zbf, P, P, P, N, 0, NP, sX, bnp1, bnp2);

    // 9: BN finalize + apply + residual
    bn_finalize<<<C, 256, 0, stream>>>(bnp1, bnp2, mean, rstd, (float)B * N);
    bn_apply_bf<<<(int)((B * sX) / 2048), 256, 0, stream>>>(zbf, x, mean, rstd, gamma, beta, out, C, N);
}

// Round 7
// 335.582 us; speedup vs baseline: 1.1516x; 1.1235x over previous
//
#include <hip/hip_runtime.h>
#include <hip/hip_bf16.h>

// B=8, C=512, N=2048, P=256.
// Round 7: register-prefetch pipelined GEMM engine (global_load->VGPR for
// tile k+1 stays in flight across compute of tile k; ds_write after compute;
// single LDS buffer). Barriers cannot drain VGPR loads, unlike
// global_load_lds (round-6 lesson). Also: theta+phi fused into ONE GEMM via
// row-concatenated weights -> thph [B][N][2P]; scores addresses theta/phi
// inside thph with lda/ldb = 2P.
// Numerics: theta/phi/scores split-bf16 (3 MFMAs, fp32-class logits);
//           g, f, y, z plain bf16 (post-softmax, not exp-amplified).

typedef __attribute__((ext_vector_type(8))) short short8;
typedef __attribute__((ext_vector_type(4))) float floatx4;

// ---------------- bf16 helpers ----------------
__device__ __forceinline__ unsigned short f2bf(float v) {
    __hip_bfloat16 h = __float2bfloat16(v);
    return *(unsigned short*)&h;
}
__device__ __forceinline__ float bf2f(unsigned short u) {
    __hip_bfloat16 h;
    *(unsigned short*)&h = u;
    return __bfloat162float(h);
}

// transpose + hi/lo split: X [R][N] fp32 -> Thi/Tlo [N][R] bf16 (batched over z)
__global__ __launch_bounds__(256) void transpose_split(
    const float* __restrict__ X, unsigned short* __restrict__ Thi,
    unsigned short* __restrict__ Tlo, int R, int N)
{
    X   += (long)blockIdx.z * R * N;
    Thi += (long)blockIdx.z * N * R;
    Tlo += (long)blockIdx.z * N * R;
    __shared__ float s[32][33];
    const int tx = threadIdx.x & 31, ty = threadIdx.x >> 5;
    const int n0 = blockIdx.x * 32, r0 = blockIdx.y * 32;
#pragma unroll
    for (int r = 0; r < 4; ++r)
        s[ty + r * 8][tx] = X[(long)(r0 + ty + r * 8) * N + n0 + tx];
    __syncthreads();
#pragma unroll
    for (int r = 0; r < 4; ++r) {
        const int n = ty + r * 8;
        const float v = s[tx][n];
        const unsigned short hi = f2bf(v);
        const unsigned short lo = f2bf(v - bf2f(hi));
        Thi[(long)(n0 + n) * R + r0 + tx] = hi;
        Tlo[(long)(n0 + n) * R + r0 + tx] = lo;
    }
}

// concat [Wth; Wph] rows and hi/lo split: out [2P][C]
__global__ __launch_bounds__(256) void split_w2(
    const float* __restrict__ Wth, const float* __restrict__ Wph,
    unsigned short* __restrict__ Whi, unsigned short* __restrict__ Wlo, int PC)
{
    const int i = blockIdx.x * 256 + threadIdx.x;
    if (i < 2 * PC) {
        const float v = (i < PC) ? Wth[i] : Wph[i - PC];
        const unsigned short hi = f2bf(v);
        Whi[i] = hi;
        Wlo[i] = f2bf(v - bf2f(hi));
    }
}

__global__ __launch_bounds__(256) void cast_bf16(
    const float* __restrict__ X, unsigned short* __restrict__ Y)
{
    const long i = ((long)blockIdx.x * 256 + threadIdx.x) * 4;
    const float4 v = *(const float4*)&X[i];
    ushort4 o;
    o.x = f2bf(v.x); o.y = f2bf(v.y); o.z = f2bf(v.z); o.w = f2bf(v.w);
    *(ushort4*)&Y[i] = o;
}

// ---------------- MFMA GEMM (register-prefetch pipeline) ----------------
// C[M][N] = A[M][K] * B[N][K]^T, bf16 K-contiguous inputs, fp32 accum.
// Tile: (FM*32) x (FN*32); 4 waves 2x2; wave tile 16FM x 16FN.
// Pipeline: global_load(k+1)->VGPR | ds_read+MFMA(k) | sync | ds_write(k+1) | sync.
// SPLIT: C = Ah*Bh + Ah*Bl + Al*Bh.
// OUTMODE: 0 fp32, 1 bf16, 2 hi/lo split bf16, 3 bf16 + BN partials scratch.
#define BK 32

template <bool SPLIT, int OUTMODE, int FM, int FN>
__global__ __launch_bounds__(256) void mfma_gemm(
    const unsigned short* __restrict__ Ahi, const unsigned short* __restrict__ Alo,
    const unsigned short* __restrict__ Bhi, const unsigned short* __restrict__ Blo,
    void* __restrict__ Cout, void* __restrict__ Cout2,
    int K, int lda, int ldb, int ldc,
    long sA, long sB, long sC,
    float* __restrict__ S1, float* __restrict__ S2)
{
    constexpr int MTM = FM * 32, MTN = FN * 32;
    constexpr int SA = FM / 2, SB = FN / 2;   // 16B segments per thread

    Ahi += (long)blockIdx.z * sA;
    Bhi += (long)blockIdx.z * sB;
    if (SPLIT) { Alo += (long)blockIdx.z * sA; Blo += (long)blockIdx.z * sB; }
    float* Cf = (float*)Cout + (long)blockIdx.z * sC;
    unsigned short* Ch = (unsigned short*)Cout + (long)blockIdx.z * sC;
    unsigned short* Cl = (unsigned short*)Cout2 + (long)blockIdx.z * sC;

    __shared__ unsigned short AsH[MTM * BK], BsH[MTN * BK];
    __shared__ unsigned short AsL[SPLIT ? MTM * BK : 8], BsL[SPLIT ? MTN * BK : 8];

    const int tid = threadIdx.x;
    const int wid = tid >> 6, lane = tid & 63;
    const int wm = (wid >> 1) * (FM * 16), wn = (wid & 1) * (FN * 16);
    const int l15 = lane & 15, quad = lane >> 4;
    const int m0 = blockIdx.y * MTM, n0 = blockIdx.x * MTN;

    // per-thread staging segments (16B each; 4 segments per 32-short row)
    int arow[SA], acol[SA], brow[SB], bcol[SB];
#pragma unroll
    for (int t = 0; t < SA; ++t) {
        const int gid = t * 256 + tid;
        arow[t] = gid >> 2; acol[t] = (gid & 3) * 8;
    }
#pragma unroll
    for (int t = 0; t < SB; ++t) {
        const int gid = t * 256 + tid;
        brow[t] = gid >> 2; bcol[t] = (gid & 3) * 8;
    }

    short8 pa[SA], pb[SB], paL[SPLIT ? SA : 1], pbL[SPLIT ? SB : 1];

    auto loadTiles = [&](int k0) {
#pragma unroll
        for (int t = 0; t < SA; ++t) {
            const long o = (long)(m0 + arow[t]) * lda + k0 + acol[t];
            pa[t] = *(const short8*)&Ahi[o];
            if (SPLIT) paL[t] = *(const short8*)&Alo[o];
        }
#pragma unroll
        for (int t = 0; t < SB; ++t) {
            const long o = (long)(n0 + brow[t]) * ldb + k0 + bcol[t];
            pb[t] = *(const short8*)&Bhi[o];
            if (SPLIT) pbL[t] = *(const short8*)&Blo[o];
        }
    };
    auto writeTiles = [&]() {
#pragma unroll
        for (int t = 0; t < SA; ++t) {
            *(short8*)&AsH[arow[t] * BK + acol[t]] = pa[t];
            if (SPLIT) *(short8*)&AsL[arow[t] * BK + acol[t]] = paL[t];
        }
#pragma unroll
        for (int t = 0; t < SB; ++t) {
            *(short8*)&BsH[brow[t] * BK + bcol[t]] = pb[t];
            if (SPLIT) *(short8*)&BsL[brow[t] * BK + bcol[t]] = pbL[t];
        }
    };

    floatx4 acc[FM][FN];
#pragma unroll
    for (int i = 0; i < FM; ++i)
#pragma unroll
        for (int j = 0; j < FN; ++j) acc[i][j] = (floatx4){0.f, 0.f, 0.f, 0.f};

    const int iters = K / BK;
    loadTiles(0);
    writeTiles();
    __syncthreads();

    for (int it = 0; it < iters; ++it) {
        if (it + 1 < iters) loadTiles((it + 1) * BK);   // VGPR loads fly across compute

        short8 ah[FM], bh[FN], al[SPLIT ? FM : 1], bl[SPLIT ? FN : 1];
#pragma unroll
        for (int i = 0; i < FM; ++i) {
            ah[i] = *(const short8*)&AsH[(wm + i * 16 + l15) * BK + quad * 8];
            if (SPLIT) al[i] = *(const short8*)&AsL[(wm + i * 16 + l15) * BK + quad * 8];
        }
#pragma unroll
        for (int j = 0; j < FN; ++j) {
            bh[j] = *(const short8*)&BsH[(wn + j * 16 + l15) * BK + quad * 8];
            if (SPLIT) bl[j] = *(const short8*)&BsL[(wn + j * 16 + l15) * BK + quad * 8];
        }
#pragma unroll
        for (int i = 0; i < FM; ++i)
#pragma unroll
            for (int j = 0; j < FN; ++j) {
                acc[i][j] = __builtin_amdgcn_mfma_f32_16x16x32_bf16(ah[i], bh[j], acc[i][j], 0, 0, 0);
                if (SPLIT) {
                    acc[i][j] = __builtin_amdgcn_mfma_f32_16x16x32_bf16(ah[i], bl[j], acc[i][j], 0, 0, 0);
                    acc[i][j] = __builtin_amdgcn_mfma_f32_16x16x32_bf16(al[i], bh[j], acc[i][j], 0, 0, 0);
                }
            }

        if (it + 1 < iters) {
            __syncthreads();          // all waves done reading LDS tile k
            writeTiles();             // vmcnt wait lands here (latency covered)
            __syncthreads();          // tile k+1 visible
        }
    }

    // C/D layout: col = lane&15, row = quad*4 + reg
#pragma unroll
    for (int i = 0; i < FM; ++i)
#pragma unroll
        for (int j = 0; j < FN; ++j) {
            const int m = m0 + wm + i * 16 + quad * 4;
            const int n = n0 + wn + j * 16 + l15;
#pragma unroll
            for (int r = 0; r < 4; ++r) {
                const float v = acc[i][j][r];
                const long idx = (long)(m + r) * ldc + n;
                if (OUTMODE == 0) {
                    Cf[idx] = v;
                } else if (OUTMODE == 1 || OUTMODE == 3) {
                    Ch[idx] = f2bf(v);
                } else {
                    const unsigned short hi = f2bf(v);
                    Ch[idx] = hi;
                    Cl[idx] = f2bf(v - bf2f(hi));
                }
            }
        }

    if (OUTMODE == 3) {
        // per-row (sum,sumsq) over this wave's 16*FN cols; scratch, no atomics
        const int slot = (blockIdx.z * gridDim.x + blockIdx.x) * 2 + (wn >> 6);
#pragma unroll
        for (int i = 0; i < FM; ++i)
#pragma unroll
            for (int r = 0; r < 4; ++r) {
                float s = 0.f, q = 0.f;
#pragma unroll
                for (int j = 0; j < FN; ++j) {
                    const float v = acc[i][j][r];
                    s += v; q += v * v;
                }
#pragma unroll
                for (int msk = 1; msk < 16; msk <<= 1) {
                    s += __shfl_xor(s, msk, 64);
                    q += __shfl_xor(q, msk, 64);
                }
                if (l15 == 0) {
                    const int row = m0 + wm + i * 16 + quad * 4 + r;
                    S1[(long)row * 256 + slot] = s;
                    S2[(long)row * 256 + slot] = q;
                }
            }
    }
}

// ---------------- softmax: fp32 chunk row -> bf16 full-f row ----------------
__global__ __launch_bounds__(256) void softmax_bf(
    const float* __restrict__ fin, unsigned short* __restrict__ fout,
    int N, int rowsPerBatch, int noff)
{
    const int b = blockIdx.x / rowsPerBatch;
    const int nc = blockIdx.x % rowsPerBatch;
    const float* p = fin + (long)blockIdx.x * N;
    unsigned short* q = fout + ((long)b * N + noff + nc) * N;
    const int tid = threadIdx.x;
    float v[8];
    float mx = -1e30f;
#pragma unroll
    for (int i = 0; i < 8; ++i) {
        v[i] = p[tid + i * 256];
        mx = fmaxf(mx, v[i]);
    }
    __shared__ float red[256];
    red[tid] = mx;
    __syncthreads();
    for (int s = 128; s > 0; s >>= 1) {
        if (tid < s) red[tid] = fmaxf(red[tid], red[tid + s]);
        __syncthreads();
    }
    mx = red[0];
    __syncthreads();
    float sum = 0.f;
#pragma unroll
    for (int i = 0; i < 8; ++i) {
        v[i] = __expf(v[i] - mx);
        sum += v[i];
    }
    red[tid] = sum;
    __syncthreads();
    for (int s = 128; s > 0; s >>= 1) {
        if (tid < s) red[tid] += red[tid + s];
        __syncthreads();
    }
    const float inv = 1.0f / red[0];
#pragma unroll
    for (int i = 0; i < 8; ++i) q[tid + i * 256] = f2bf(v[i] * inv);
}

// ---------------- BN finalize + apply ----------------
__global__ __launch_bounds__(256) void bn_finalize(
    const float* __restrict__ p1, const float* __restrict__ p2,
    float* __restrict__ mean, float* __restrict__ rstd, float cnt)
{
    const int c = blockIdx.x, t = threadIdx.x;
    __shared__ float rs[256], rq[256];
    rs[t] = p1[(long)c * 256 + t];
    rq[t] = p2[(long)c * 256 + t];
    __syncthreads();
    for (int st = 128; st > 0; st >>= 1) {
        if (t < st) { rs[t] += rs[t + st]; rq[t] += rq[t + st]; }
        __syncthreads();
    }
    if (t == 0) {
        const float m = rs[0] / cnt;
        mean[c] = m;
        rstd[c] = rsqrtf(rq[0] / cnt - m * m + 1e-5f);
    }
}

__global__ __launch_bounds__(256) void bn_apply_bf(
    const unsigned short* __restrict__ z, const float* __restrict__ x,
    const float* __restrict__ mean, const float* __restrict__ rstd,
    const float* __restrict__ gamma, const float* __restrict__ beta,
    float* __restrict__ out, int C, int N)
{
    const long i = ((long)blockIdx.x * 256 + threadIdx.x) * 8;
    const int c = (int)((i / N) % C);
    const float mu = mean[c], rs = rstd[c], ga = gamma[c], be = beta[c];
    const ushort4 z0 = *(const ushort4*)&z[i];
    const ushort4 z1 = *(const ushort4*)&z[i + 4];
    const float4 x0 = *(const float4*)&x[i];
    const float4 x1 = *(const float4*)&x[i + 4];
    float4 o0, o1;
    o0.x = (bf2f(z0.x) - mu) * rs * ga + be + x0.x;
    o0.y = (bf2f(z0.y) - mu) * rs * ga + be + x0.y;
    o0.z = (bf2f(z0.z) - mu) * rs * ga + be + x0.z;
    o0.w = (bf2f(z0.w) - mu) * rs * ga + be + x0.w;
    o1.x = (bf2f(z1.x) - mu) * rs * ga + be + x1.x;
    o1.y = (bf2f(z1.y) - mu) * rs * ga + be + x1.y;
    o1.z = (bf2f(z1.z) - mu) * rs * ga + be + x1.z;
    o1.w = (bf2f(z1.w) - mu) * rs * ga + be + x1.w;
    *(float4*)&out[i] = o0;
    *(float4*)&out[i + 4] = o1;
}

extern "C" void kernel_launch(void* const* d_in, const int* in_sizes, int n_in,
                              void* d_out, int out_size, void* d_ws, size_t ws_size,
                              hipStream_t stream)
{
    const int B = 8, C = 512, N = 2048, P = 256;
    const int NC = 512;                       // f row-chunk
    const float* x      = (const float*)d_in[0];
    const float* Wg     = (const float*)d_in[1];
    const float* Wtheta = (const float*)d_in[2];
    const float* Wphi   = (const float*)d_in[3];
    const float* Wz     = (const float*)d_in[4];
    const float* gamma  = (const float*)d_in[5];
    const float* beta   = (const float*)d_in[6];
    float* out = (float*)d_out;

    // ---- workspace layout (float units), ~152.6 MB total ----
    float* ws = (float*)d_ws;
    const long NCle = (long)N * C;            // 1,048,576 per batch (= N*2P)
    const long NP   = (long)N * P;            // 524,288 per batch
    const long R0   = (long)B * NCle;         // 8.39M floats
    unsigned short* xtH   = (unsigned short*)ws;                // B*N*C
    unsigned short* xtL   = xtH + B * NCle;
    float*          f32c  = ws;                                 // aliases xt (dead after g)
    unsigned short* zbf   = (unsigned short*)ws;                // aliases f32c
    unsigned short* thphH = (unsigned short*)(ws + R0);         // B*N*2P
    unsigned short* thphL = thphH + B * NCle;                   // B*N*2P
    unsigned short* gbf   = (unsigned short*)(ws + 2 * R0);     // B*P*N
    unsigned short* fbf   = gbf + B * NP;                       // B*N*N
    unsigned short* ybf   = fbf + (long)B * N * N;              // B*N*P
    unsigned short* W2H   = ybf + B * NP;                       // 2P*C
    unsigned short* W2L   = W2H + 2L * P * C;
    unsigned short* WgB   = W2L + 2L * P * C;                   // P*C
    unsigned short* WzB   = WgB + (long)P * C;
    // BN scratch aliases thph region (dead after scores)
    float*          bnp1  = ws + R0;           // [C][256]
    float*          bnp2  = bnp1 + (long)C * 256;
    float*          mean  = bnp2 + (long)C * 256;
    float*          rstd  = mean + C;

    const long sX = (long)C * N;
    const int  P2 = 2 * P;                    // 512

    // 1: transpose+split x -> xT hi/lo [B][N][C]
    transpose_split<<<dim3(N / 32, C / 32, B), 256, 0, stream>>>(x, xtH, xtL, C, N);
    // 2: weight preps (W2 = [Wth; Wph] rows, split; Wg/Wz plain bf16)
    split_w2<<<(2 * P * C + 255) / 256, 256, 0, stream>>>(Wtheta, Wphi, W2H, W2L, P * C);
    cast_bf16<<<P * C / 1024, 256, 0, stream>>>(Wg, WgB);
    cast_bf16<<<P * C / 1024, 256, 0, stream>>>(Wz, WzB);

    // 3: thph [B][N][2P] = xT @ W2^T (split in, split out); 128x128 tiles, 512 blocks
    mfma_gemm<true, 2, 4, 4><<<dim3(P2 / 128, N / 128, B), 256, 0, stream>>>(
        xtH, xtL, W2H, W2L, thphH, thphL, C, C, C, P2, NCle, 0, NCle, nullptr, nullptr);
    // 4: g [B][P][N] = Wg @ xT^T (plain, bf16 out); 64x128 tiles, 512 blocks
    mfma_gemm<false, 1, 2, 4><<<dim3(N / 128, P / 64, B), 256, 0, stream>>>(
        WgB, WgB, xtH, xtH, gbf, gbf, C, C, C, N, 0, NCle, NP, nullptr, nullptr);

    // 5: scores (split) + softmax, chunked (f32c aliases xt: xt dead now)
    //    theta rows: thph[:, 0:256]; phi rows: thph[:, 256:512]; lda=ldb=2P
    for (int c = 0; c < N / NC; ++c) {
        mfma_gemm<true, 0, 4, 2><<<dim3(N / 64, NC / 128, B), 256, 0, stream>>>(
            thphH + (long)c * NC * P2, thphL + (long)c * NC * P2,
            thphH + P, thphL + P, f32c, f32c,
            P, P2, P2, N, NCle, NCle, (long)NC * N, nullptr, nullptr);
        softmax_bf<<<B * NC, 256, 0, stream>>>(f32c, fbf, N, NC, c * NC);
    }

    // 6: yT [B][N][P] = fbf @ g^T (plain, bf16 out); 64x128 tiles, 512 blocks
    mfma_gemm<false, 1, 2, 4><<<dim3(P / 128, N / 64, B), 256, 0, stream>>>(
        fbf, fbf, gbf, gbf, ybf, ybf, N, N, N, P, (long)N * N, NP, NP, nullptr, nullptr);

    // 7: z [B][C][N] bf16 = Wz @ yT^T, BN partials to scratch (thph dead now)
    mfma_gemm<false, 3, 4, 4><<<dim3(N / 128, C / 128, B), 256, 0, stream>>>(
        WzB, WzB, ybf, ybf, zbf, zbf, P, P, P, N, 0, NP, sX, bnp1, bnp2);

    // 8: BN finalize + apply + residual
    bn_finalize<<<C, 256, 0, stream>>>(bnp1, bnp2, mean, rstd, (float)B * N);
    bn_apply_bf<<<(int)((B * sX) / 2048), 256, 0, stream>>>(zbf, x, mean, rstd, gamma, beta, out, C, N);
}